// Round 20
// baseline (1236.128 us; speedup 1.0000x reference)
//
#include <hip/hip_runtime.h>

#define IN 10
#define HID 128
#define OUT 4

// Dequantized f32 weights (static device globals; rewritten every launch).
__device__ float g_W1qf[HID * IN];
__device__ float g_W2qf[HID * HID];
__device__ float g_W3qf[OUT * HID];

// ---------- asm-protected f32 ops (immune to fast-math/reassoc/contract) ----------
__device__ __forceinline__ float f_fma(float a, float b, float c) {
    float d; asm("v_fma_f32 %0, %1, %2, %3" : "=v"(d) : "v"(a), "v"(b), "v"(c)); return d;
}
__device__ __forceinline__ float f_mul(float a, float b) {
    float d; asm("v_mul_f32 %0, %1, %2" : "=v"(d) : "v"(a), "v"(b)); return d;
}
__device__ __forceinline__ float f_add(float a, float b) {
    float d; asm("v_add_f32 %0, %1, %2" : "=v"(d) : "v"(a), "v"(b)); return d;
}
__device__ __forceinline__ float f_sub(float a, float b) {
    float d; asm("v_sub_f32 %0, %1, %2" : "=v"(d) : "v"(a), "v"(b)); return d;
}
__device__ __forceinline__ float f_rndne(float a) {   // round half to even = np.round
    float d; asm("v_rndne_f32 %0, %1" : "=v"(d) : "v"(a)); return d;
}
__device__ __forceinline__ float f_rcp(float a) {
    float d; asm("v_rcp_f32 %0, %1" : "=v"(d) : "v"(a)); return d;
}
// Exact byte->float converts (values <=255 exact; we use codes <=15).
__device__ __forceinline__ float cvt_ub0(unsigned int u) {
    float d; asm("v_cvt_f32_ubyte0 %0, %1" : "=v"(d) : "v"(u)); return d;
}
__device__ __forceinline__ float cvt_ub1(unsigned int u) {
    float d; asm("v_cvt_f32_ubyte1 %0, %1" : "=v"(d) : "v"(u)); return d;
}
__device__ __forceinline__ float cvt_ub2(unsigned int u) {
    float d; asm("v_cvt_f32_ubyte2 %0, %1" : "=v"(d) : "v"(u)); return d;
}
__device__ __forceinline__ float cvt_ub3(unsigned int u) {
    float d; asm("v_cvt_f32_ubyte3 %0, %1" : "=v"(d) : "v"(u)); return d;
}

// ---------- VOP3P packed f32 (all vector sources must be VGPR PAIRS) ----------
// Each half executes a full-precision IEEE v_fma_f32 -> per-row bit-identical
// to scalar. op_sel/op_sel_hi select which half of src1 (weight pair) is used:
//   pk_fma_lo: both result halves use b.lo   (weight k)
//   pk_fma_hi: both result halves use b.hi   (weight k+1)
__device__ __forceinline__ void pk_fma_lo(float2& c, float2 a, float2 b) {
    asm("v_pk_fma_f32 %0, %1, %2, %0 op_sel_hi:[1,0,1]" : "+v"(c) : "v"(a), "v"(b));
}
__device__ __forceinline__ void pk_fma_hi(float2& c, float2 a, float2 b) {
    asm("v_pk_fma_f32 %0, %1, %2, %0 op_sel:[0,1,0] op_sel_hi:[1,1,1]" : "+v"(c) : "v"(a), "v"(b));
}
__device__ __forceinline__ float2 pk_mul_lo(float2 a, float2 b) {   // {a.x*b.x, a.y*b.x}
    float2 d; asm("v_pk_mul_f32 %0, %1, %2 op_sel_hi:[1,0]" : "=v"(d) : "v"(a), "v"(b));
    return d;
}
__device__ __forceinline__ float2 lo2(float4 q) { return make_float2(q.x, q.y); }
__device__ __forceinline__ float2 hi2(float4 q) { return make_float2(q.z, q.w); }

// CR reciprocal / CR divide (Markstein). d.y = correctly-rounded 1/s.
struct DivCR { float y, ns; };
__device__ __forceinline__ DivCR make_div(float s) {
    DivCR d;
    d.ns = f_sub(0.0f, s);
    float y0 = f_rcp(s);
    float e0 = f_fma(d.ns, y0, 1.0f);
    float y1 = f_fma(e0, y0, y0);
    float e1 = f_fma(d.ns, y1, 1.0f);
    d.y = f_fma(e1, y1, y1);
    return d;
}
__device__ __forceinline__ float div_cr(float h, DivCR d) {
    float q0 = f_mul(h, d.y);
    float r  = f_fma(d.ns, q0, h);
    return f_fma(r, d.y, q0);
}

// prep: bit-identical to R11-R17 (passed).
__global__ void prep_kernel(const float* __restrict__ W1,
                            const float* __restrict__ W2,
                            const float* __restrict__ W3) {
    __shared__ float red[256];
    __shared__ float sS;
    const int t = threadIdx.x;
    const int which = blockIdx.x;

    const float* W; float* Wo; int n;
    if (which == 0)      { W = W1; Wo = g_W1qf; n = HID * IN; }
    else if (which == 1) { W = W2; Wo = g_W2qf; n = HID * HID; }
    else                 { W = W3; Wo = g_W3qf; n = OUT * HID; }

    float mx = 0.f;
    for (int i = t; i < n; i += 256) mx = fmaxf(mx, fabsf(W[i]));
    red[t] = mx;
    __syncthreads();
    for (int s = 128; s > 0; s >>= 1) {
        if (t < s) red[t] = fmaxf(red[t], red[t + s]);
        __syncthreads();
    }
    if (t == 0) {
        DivCR d7 = make_div(7.0f);
        sS = div_cr(red[0], d7);
    }
    __syncthreads();
    const float s = sS;
    const float rs = make_div(s).y;

    for (int i = t; i < n; i += 256) {
        float r = f_rndne(f_mul(W[i], rs));
        r = fminf(7.f, fmaxf(-7.f, r));
        Wo[i] = f_mul(r, s);
    }
}

// Quant epilogue: h -> uint code (bit-identical op sequence to R11-R17).
__device__ __forceinline__ unsigned int quant_code(float acc, float bias, float recip) {
    float h = f_add(acc, bias);
    float r = f_rndne(f_mul(h, recip));
    r = fminf(15.f, fmaxf(0.f, r));
    return (unsigned int)r;
}

// 2 rows/thread in VOP3P lo/hi halves: weight pairs consumed via op_sel, FMA
// inst + ds_reads per row halved. 512 threads, 64 KB LDS -> 16 waves/CU.
__global__ __launch_bounds__(512, 4) void mlp_kernel(
    const float* __restrict__ m,
    const float* __restrict__ b1,
    const float* __restrict__ b2,
    const float* __restrict__ b3,
    const float* __restrict__ s_act1,
    const float* __restrict__ s_act2,
    float* __restrict__ out, int nrows)
{
    __shared__ float sW2[HID * HID];   // 64 KB

    const int t = threadIdx.x;

    // Cooperative stage (coalesced float4), BEFORE any early-out.
    {
        const float4* src = (const float4*)g_W2qf;
        float4* dst = (float4*)sW2;
        #pragma unroll
        for (int i = 0; i < 8; ++i) dst[t + 512 * i] = src[t + 512 * i];
    }
    __syncthreads();

    const int rowA = blockIdx.x * 1024 + t;
    const int rowB = rowA + 512;
    const int rA = rowA < nrows ? rowA : (nrows - 1);   // clamp: compute valid, store guarded
    const int rB = rowB < nrows ? rowB : (nrows - 1);

    const float s1 = s_act1[0];
    const float s2 = s_act2[0];
    const float r1 = make_div(s1).y;        // CR 1/s1
    const float r2 = make_div(s2).y;        // CR 1/s2
    float2 s1p; s1p.x = s1; s1p.y = s1;     // pk broadcast pairs
    float2 s2p; s2p.x = s2; s2p.y = s2;

    // Input rows (40B each, 8-aligned) packed as {rowA, rowB} pairs.
    float2 xp[IN];
    {
        const float2* ma = (const float2*)(m + (size_t)rA * IN);
        const float2* mb = (const float2*)(m + (size_t)rB * IN);
        #pragma unroll
        for (int i = 0; i < 5; ++i) {
            float2 va = ma[i], vb = mb[i];
            xp[2 * i].x     = va.x; xp[2 * i].y     = vb.x;
            xp[2 * i + 1].x = va.y; xp[2 * i + 1].y = vb.y;
        }
    }

    // ---- Layer 1: 4-way j-ILP pk chains -> packed codes (32+32 VGPR words) ----
    unsigned int actwA[32], actwB[32];
    #pragma unroll
    for (int g = 0; g < 32; ++g) {
        const float2* w0p = (const float2*)&g_W1qf[(4 * g + 0) * IN];
        const float2* w1p = (const float2*)&g_W1qf[(4 * g + 1) * IN];
        const float2* w2p = (const float2*)&g_W1qf[(4 * g + 2) * IN];
        const float2* w3p = (const float2*)&g_W1qf[(4 * g + 3) * IN];
        float2 a0 = make_float2(0.f, 0.f), a1c = a0, a2c = a0, a3c = a0;
        #pragma unroll
        for (int kp = 0; kp < 5; ++kp) {     // weight pair {k, k+1}
            float2 wq0 = w0p[kp], wq1 = w1p[kp], wq2 = w2p[kp], wq3 = w3p[kp];
            pk_fma_lo(a0,  xp[2 * kp],     wq0);
            pk_fma_hi(a0,  xp[2 * kp + 1], wq0);
            pk_fma_lo(a1c, xp[2 * kp],     wq1);
            pk_fma_hi(a1c, xp[2 * kp + 1], wq1);
            pk_fma_lo(a2c, xp[2 * kp],     wq2);
            pk_fma_hi(a2c, xp[2 * kp + 1], wq2);
            pk_fma_lo(a3c, xp[2 * kp],     wq3);
            pk_fma_hi(a3c, xp[2 * kp + 1], wq3);
        }
        unsigned int cA0 = quant_code(a0.x,  b1[4 * g + 0], r1);
        unsigned int cA1 = quant_code(a1c.x, b1[4 * g + 1], r1);
        unsigned int cA2 = quant_code(a2c.x, b1[4 * g + 2], r1);
        unsigned int cA3 = quant_code(a3c.x, b1[4 * g + 3], r1);
        actwA[g] = cA0 | (cA1 << 8) | (cA2 << 16) | (cA3 << 24);
        unsigned int cB0 = quant_code(a0.y,  b1[4 * g + 0], r1);
        unsigned int cB1 = quant_code(a1c.y, b1[4 * g + 1], r1);
        unsigned int cB2 = quant_code(a2c.y, b1[4 * g + 2], r1);
        unsigned int cB3 = quant_code(a3c.y, b1[4 * g + 3], r1);
        actwB[g] = cB0 | (cB1 << 8) | (cB2 << 16) | (cB3 << 24);
        __builtin_amdgcn_sched_barrier(0);   // bound L1 live ranges
    }

    // ---- Layer 2 (LDS weights, 4-way j-ILP, pk over the row pair) + fused L3 ----
    float2 o0 = make_float2(0.f, 0.f), o1 = o0, o2 = o0, o3 = o0;

    #pragma unroll 1
    for (int g = 0; g < 32; ++g) {
        const float4* w0 = (const float4*)&sW2[(4 * g + 0) * HID];
        const float4* w1 = (const float4*)&sW2[(4 * g + 1) * HID];
        const float4* w2 = (const float4*)&sW2[(4 * g + 2) * HID];
        const float4* w3 = (const float4*)&sW2[(4 * g + 3) * HID];
        float2 a0 = make_float2(0.f, 0.f), a1c = a0, a2c = a0, a3c = a0;
        #pragma unroll
        for (int kk = 0; kk < 32; ++kk) {
            float4 q0 = w0[kk];
            float4 q1 = w1[kk];
            float4 q2 = w2[kk];
            float4 q3 = w3[kk];
            const unsigned int uA = actwA[kk];     // static index -> VGPR
            const unsigned int uB = actwB[kk];
            float2 cv0, cv1, cv2, cv3;
            cv0.x = cvt_ub0(uA); cv0.y = cvt_ub0(uB);
            cv1.x = cvt_ub1(uA); cv1.y = cvt_ub1(uB);
            cv2.x = cvt_ub2(uA); cv2.y = cvt_ub2(uB);
            cv3.x = cvt_ub3(uA); cv3.y = cvt_ub3(uB);
            float2 av0 = pk_mul_lo(cv0, s1p);      // == f_mul((float)c, s1) per half
            float2 av1 = pk_mul_lo(cv1, s1p);
            float2 av2 = pk_mul_lo(cv2, s1p);
            float2 av3 = pk_mul_lo(cv3, s1p);
            float2 q0l = lo2(q0), q0h = hi2(q0);
            float2 q1l = lo2(q1), q1h = hi2(q1);
            float2 q2l = lo2(q2), q2h = hi2(q2);
            float2 q3l = lo2(q3), q3h = hi2(q3);
            pk_fma_lo(a0,  av0, q0l);
            pk_fma_hi(a0,  av1, q0l);
            pk_fma_lo(a0,  av2, q0h);
            pk_fma_hi(a0,  av3, q0h);
            pk_fma_lo(a1c, av0, q1l);
            pk_fma_hi(a1c, av1, q1l);
            pk_fma_lo(a1c, av2, q1h);
            pk_fma_hi(a1c, av3, q1h);
            pk_fma_lo(a2c, av0, q2l);
            pk_fma_hi(a2c, av1, q2l);
            pk_fma_lo(a2c, av2, q2h);
            pk_fma_hi(a2c, av3, q2h);
            pk_fma_lo(a3c, av0, q3l);
            pk_fma_hi(a3c, av1, q3l);
            pk_fma_lo(a3c, av2, q3h);
            pk_fma_hi(a3c, av3, q3h);
            __builtin_amdgcn_sched_barrier(0);     // cap staged ds_reads at 4xfloat4
        }
        unsigned int cA0 = quant_code(a0.x,  b2[4 * g + 0], r2);
        unsigned int cA1 = quant_code(a1c.x, b2[4 * g + 1], r2);
        unsigned int cA2 = quant_code(a2c.x, b2[4 * g + 2], r2);
        unsigned int cA3 = quant_code(a3c.x, b2[4 * g + 3], r2);
        unsigned int cB0 = quant_code(a0.y,  b2[4 * g + 0], r2);
        unsigned int cB1 = quant_code(a1c.y, b2[4 * g + 1], r2);
        unsigned int cB2 = quant_code(a2c.y, b2[4 * g + 2], r2);
        unsigned int cB3 = quant_code(a3c.y, b2[4 * g + 3], r2);
        float2 cp0; cp0.x = (float)cA0; cp0.y = (float)cB0;
        float2 cp1; cp1.x = (float)cA1; cp1.y = (float)cB1;
        float2 cp2; cp2.x = (float)cA2; cp2.y = (float)cB2;
        float2 cp3; cp3.x = (float)cA3; cp3.y = (float)cB3;
        float2 vp0 = pk_mul_lo(cp0, s2p);          // == f_mul((float)c, s2) per half
        float2 vp1 = pk_mul_lo(cp1, s2p);
        float2 vp2 = pk_mul_lo(cp2, s2p);
        float2 vp3 = pk_mul_lo(cp3, s2p);
        // Fused L3: ascending k = 4g..4g+3; weight quads consumed as 2 pairs.
        const float2* u0p = (const float2*)&g_W3qf[0 * HID + 4 * g];
        const float2* u1p = (const float2*)&g_W3qf[1 * HID + 4 * g];
        const float2* u2p = (const float2*)&g_W3qf[2 * HID + 4 * g];
        const float2* u3p = (const float2*)&g_W3qf[3 * HID + 4 * g];
        float2 u0a = u0p[0], u0b = u0p[1];
        float2 u1a = u1p[0], u1b = u1p[1];
        float2 u2a = u2p[0], u2b = u2p[1];
        float2 u3a = u3p[0], u3b = u3p[1];
        pk_fma_lo(o0, vp0, u0a);
        pk_fma_hi(o0, vp1, u0a);
        pk_fma_lo(o0, vp2, u0b);
        pk_fma_hi(o0, vp3, u0b);
        pk_fma_lo(o1, vp0, u1a);
        pk_fma_hi(o1, vp1, u1a);
        pk_fma_lo(o1, vp2, u1b);
        pk_fma_hi(o1, vp3, u1b);
        pk_fma_lo(o2, vp0, u2a);
        pk_fma_hi(o2, vp1, u2a);
        pk_fma_lo(o2, vp2, u2b);
        pk_fma_hi(o2, vp3, u2b);
        pk_fma_lo(o3, vp0, u3a);
        pk_fma_hi(o3, vp1, u3a);
        pk_fma_lo(o3, vp2, u3b);
        pk_fma_hi(o3, vp3, u3b);
    }

    if (rowA < nrows) {
        float4 o;
        o.x = f_add(o0.x, b3[0]);
        o.y = f_add(o1.x, b3[1]);
        o.z = f_add(o2.x, b3[2]);
        o.w = f_add(o3.x, b3[3]);
        *(float4*)(out + (size_t)rowA * OUT) = o;
    }
    if (rowB < nrows) {
        float4 o;
        o.x = f_add(o0.y, b3[0]);
        o.y = f_add(o1.y, b3[1]);
        o.z = f_add(o2.y, b3[2]);
        o.w = f_add(o3.y, b3[3]);
        *(float4*)(out + (size_t)rowB * OUT) = o;
    }
}

extern "C" void kernel_launch(void* const* d_in, const int* in_sizes, int n_in,
                              void* d_out, int out_size, void* d_ws, size_t ws_size,
                              hipStream_t stream) {
    const float* m  = (const float*)d_in[0];
    const float* W1 = (const float*)d_in[1];
    const float* b1 = (const float*)d_in[2];
    const float* W2 = (const float*)d_in[3];
    const float* b2 = (const float*)d_in[4];
    const float* W3 = (const float*)d_in[5];
    const float* b3 = (const float*)d_in[6];
    const float* s1 = (const float*)d_in[7];
    const float* s2 = (const float*)d_in[8];
    const int nrows = in_sizes[0] / IN;

    prep_kernel<<<3, 256, 0, stream>>>(W1, W2, W3);
    const int nblk = (nrows + 1023) / 1024;
    mlp_kernel<<<nblk, 512, 0, stream>>>(m, b1, b2, b3, s1, s2, (float*)d_out, nrows);
}